// Round 1
// baseline (997.070 us; speedup 1.0000x reference)
//
#include <hip/hip_runtime.h>

// ---------------- problem constants (fixed by setup_inputs) ----------------
#define T_TOK 2048
#define NEXP  8
#define H_DIM 1024
#define I_DIM 4096

#define KP13 (H_DIM/8)     // 128 packed rows, W13
#define N13  (2*I_DIM)     // 8192 cols, W13
#define KP2  (I_DIM/8)     // 512 packed rows, W2
#define N2   (H_DIM)       // 1024 cols, W2
#define NG13 8             // H/128 groups
#define NG2  32            // I/128 groups

// ---------------- tiles ----------------
#define BM 128
#define BN 64
#define BK 32
#define LDA 40             // padded lds stride (bf16 elems)
#define LDB 40
#define MT1 (T_TOK/BM)     // 16 worst-case m-tiles per expert
#define MT2 (T_TOK/BM)     // 16

typedef __bf16 bf16x8 __attribute__((ext_vector_type(8)));
typedef float  f32x4  __attribute__((ext_vector_type(4)));
typedef int    i32x4  __attribute__((ext_vector_type(4)));

// ---------------- workspace layout (bytes) ----------------
#define WS_COUNTS 0
#define WS_OFFS   64
#define WS_CURS   128
#define WS_TOKE   256
#define WS_TOKW   (WS_TOKE  + 2*T_TOK*4)
#define WS_PLIST  (WS_TOKW  + 2*T_TOK*4)
#define WS_PW     (WS_PLIST + 2*T_TOK*4)
#define WS_ACT    131072                   // bf16 act[4096][I_DIM] = 32 MiB

// =====================================================================
// Routing: top-2 of logits; normalized pair weights (softmax cancels)
// =====================================================================
__global__ void k_route(const float* __restrict__ logits,
                        int* __restrict__ counts,
                        int* __restrict__ tok_e, float* __restrict__ tok_w) {
    int t = blockIdx.x * blockDim.x + threadIdx.x;
    if (t >= T_TOK) return;
    float l[NEXP];
    #pragma unroll
    for (int e = 0; e < NEXP; e++) l[e] = logits[t * NEXP + e];
    int i0 = 0; float b0 = l[0];
    #pragma unroll
    for (int e = 1; e < NEXP; e++) if (l[e] > b0) { b0 = l[e]; i0 = e; }
    int i1 = -1; float b1 = -1e30f;
    #pragma unroll
    for (int e = 0; e < NEXP; e++) if (e != i0 && l[e] > b1) { b1 = l[e]; i1 = e; }
    float w1 = 1.f / (1.f + __expf(b0 - b1));   // p1/(p0+p1)
    float w0 = 1.f - w1;
    tok_e[2*t] = i0; tok_e[2*t+1] = i1;
    tok_w[2*t] = w0; tok_w[2*t+1] = w1;
    atomicAdd(&counts[i0], 1);
    atomicAdd(&counts[i1], 1);
}

__global__ void k_scan(const int* __restrict__ counts,
                       int* __restrict__ offs, int* __restrict__ curs) {
    if (blockIdx.x == 0 && threadIdx.x == 0) {
        int s = 0;
        for (int e = 0; e < NEXP; e++) { offs[e] = s; curs[e] = s; s += counts[e]; }
        offs[NEXP] = s;   // == 4096
    }
}

__global__ void k_scatter(const int* __restrict__ tok_e, const float* __restrict__ tok_w,
                          int* __restrict__ curs,
                          int* __restrict__ plist, float* __restrict__ pw) {
    int t = blockIdx.x * blockDim.x + threadIdx.x;
    if (t >= T_TOK) return;
    #pragma unroll
    for (int s = 0; s < 2; s++) {
        int e = tok_e[2*t+s];
        int pos = atomicAdd(&curs[e], 1);
        plist[pos] = t;
        pw[pos] = tok_w[2*t+s];
    }
}

// =====================================================================
// GEMM1: act[p, n] = w_p * silu(x@Wg)[p,n] * (x@Wu)[p,n]  (per expert)
// =====================================================================
__global__ __launch_bounds__(256) void k_gemm1(
    const float* __restrict__ x,
    const int*   __restrict__ w13q,
    const float* __restrict__ w13s,
    const int*   __restrict__ g13,
    const int*   __restrict__ offs,
    const int*   __restrict__ plist,
    const float* __restrict__ pw,
    __bf16*      __restrict__ act) {

    const int e  = blockIdx.x / MT1;
    const int mt = blockIdx.x % MT1;
    const int mstart = offs[e], mend = offs[e+1];
    const int m0 = mstart + mt * BM;
    if (m0 >= mend) return;
    int mcount = mend - m0; if (mcount > BM) mcount = BM;
    const int n0 = blockIdx.y * BN;   // act column base (gate col n0, up col I+n0)

    __shared__ __align__(16) __bf16 As[BM][LDA];
    __shared__ __align__(16) __bf16 Bg[BN][LDB];
    __shared__ __align__(16) __bf16 Bu[BN][LDB];
    __shared__ float sg[NG13][BN];
    __shared__ float su[NG13][BN];
    __shared__ int   toks[BM];
    __shared__ float wts[BM];

    const int tid = threadIdx.x;

    // preload scales for this n-range + token list
    for (int i = tid; i < NG13 * BN; i += 256) {
        int g = i / BN, nl = i % BN;
        size_t base = (size_t)e * NG13 * N13 + (size_t)g * N13;
        sg[g][nl] = w13s[base + n0 + nl];
        su[g][nl] = w13s[base + I_DIM + n0 + nl];
    }
    for (int m = tid; m < BM; m += 256) {
        if (m < mcount) { toks[m] = plist[m0 + m]; wts[m] = pw[m0 + m]; }
        else            { toks[m] = 0;             wts[m] = 0.f; }
    }
    __syncthreads();

    f32x4 accg[2][4], accu[2][4];
    #pragma unroll
    for (int i = 0; i < 2; i++)
        #pragma unroll
        for (int j = 0; j < 4; j++) { accg[i][j] = (f32x4)(0.f); accu[i][j] = (f32x4)(0.f); }

    const int wv = tid >> 6, lane = tid & 63;
    const int lrow = lane & 15, quad = lane >> 4;
    const int mbase = wv * 32;

    for (int k0 = 0; k0 < H_DIM; k0 += BK) {
        // ---- stage A: x (fp32) -> bf16 LDS ----
        {
            const int m = tid >> 1, half = tid & 1;
            __align__(16) __bf16 th[16];
            if (m < mcount) {
                const f32x4* s4 = reinterpret_cast<const f32x4*>(
                    x + (size_t)toks[m] * H_DIM + k0 + half * 16);
                f32x4 v0 = s4[0], v1 = s4[1], v2 = s4[2], v3 = s4[3];
                #pragma unroll
                for (int i = 0; i < 4; i++) {
                    th[i]    = (__bf16)v0[i];
                    th[4+i]  = (__bf16)v1[i];
                    th[8+i]  = (__bf16)v2[i];
                    th[12+i] = (__bf16)v3[i];
                }
            } else {
                #pragma unroll
                for (int i = 0; i < 16; i++) th[i] = (__bf16)0.f;
            }
            *reinterpret_cast<f32x4*>(&As[m][half*16])     = *reinterpret_cast<f32x4*>(&th[0]);
            *reinterpret_cast<f32x4*>(&As[m][half*16 + 8]) = *reinterpret_cast<f32x4*>(&th[8]);
        }
        // ---- stage B: dequant int4 -> bf16 LDS (transposed [n][k]) ----
        {
            const int nl = tid & 63, kpl = tid >> 6;
            const int kp = (k0 >> 3) + kpl;
            const size_t qbase = (size_t)e * KP13 * N13 + (size_t)kp * N13 + n0 + nl;
            const int qg = w13q[qbase];
            const int qu = w13q[qbase + I_DIM];
            const i32x4* gp = reinterpret_cast<const i32x4*>(g13 + e * H_DIM + k0 + kpl * 8);
            i32x4 ga = gp[0], gb = gp[1];
            int gsv[8] = {ga.x, ga.y, ga.z, ga.w, gb.x, gb.y, gb.z, gb.w};
            __align__(16) __bf16 tg[8], tu[8];
            #pragma unroll
            for (int j = 0; j < 8; j++) {
                float s0 = sg[gsv[j]][nl];
                float s1 = su[gsv[j]][nl];
                tg[j] = (__bf16)((float)(((qg >> (4*j)) & 15) - 8) * s0);
                tu[j] = (__bf16)((float)(((qu >> (4*j)) & 15) - 8) * s1);
            }
            *reinterpret_cast<f32x4*>(&Bg[nl][kpl*8]) = *reinterpret_cast<f32x4*>(tg);
            *reinterpret_cast<f32x4*>(&Bu[nl][kpl*8]) = *reinterpret_cast<f32x4*>(tu);
        }
        __syncthreads();
        // ---- MFMA ----
        {
            bf16x8 a0 = *reinterpret_cast<const bf16x8*>(&As[mbase + lrow][quad*8]);
            bf16x8 a1 = *reinterpret_cast<const bf16x8*>(&As[mbase + 16 + lrow][quad*8]);
            #pragma unroll
            for (int j = 0; j < 4; j++) {
                bf16x8 bg = *reinterpret_cast<const bf16x8*>(&Bg[j*16 + lrow][quad*8]);
                bf16x8 bu = *reinterpret_cast<const bf16x8*>(&Bu[j*16 + lrow][quad*8]);
                accg[0][j] = __builtin_amdgcn_mfma_f32_16x16x32_bf16(a0, bg, accg[0][j], 0, 0, 0);
                accg[1][j] = __builtin_amdgcn_mfma_f32_16x16x32_bf16(a1, bg, accg[1][j], 0, 0, 0);
                accu[0][j] = __builtin_amdgcn_mfma_f32_16x16x32_bf16(a0, bu, accu[0][j], 0, 0, 0);
                accu[1][j] = __builtin_amdgcn_mfma_f32_16x16x32_bf16(a1, bu, accu[1][j], 0, 0, 0);
            }
        }
        __syncthreads();
    }

    // ---- epilogue: silu(g)*u * routing weight -> bf16 act ----
    #pragma unroll
    for (int i = 0; i < 2; i++)
        #pragma unroll
        for (int j = 0; j < 4; j++)
            #pragma unroll
            for (int r = 0; r < 4; r++) {
                int row = mbase + i*16 + quad*4 + r;
                if (row < mcount) {
                    float g = accg[i][j][r];
                    float u = accu[i][j][r];
                    float a = (g / (1.f + __expf(-g))) * u * wts[row];
                    act[(size_t)(m0 + row) * I_DIM + n0 + j*16 + lrow] = (__bf16)a;
                }
            }
}

// =====================================================================
// GEMM2: out[tok, h] += (act @ dequant(W2))[p, h]   (atomic combine)
// =====================================================================
__global__ __launch_bounds__(256) void k_gemm2(
    const __bf16* __restrict__ act,
    const int*    __restrict__ w2q,
    const float*  __restrict__ w2s,
    const int*    __restrict__ g2,
    const int*    __restrict__ offs,
    const int*    __restrict__ plist,
    float*        __restrict__ out) {

    const int e  = blockIdx.x / MT2;
    const int mt = blockIdx.x % MT2;
    const int mstart = offs[e], mend = offs[e+1];
    const int m0 = mstart + mt * BM;
    if (m0 >= mend) return;
    int mcount = mend - m0; if (mcount > BM) mcount = BM;
    const int n0 = blockIdx.y * BN;   // H column base

    __shared__ __align__(16) __bf16 As[BM][LDA];
    __shared__ __align__(16) __bf16 Bt[BN][LDB];
    __shared__ float s2[NG2][BN];
    __shared__ int   toks[BM];

    const int tid = threadIdx.x;

    for (int i = tid; i < NG2 * BN; i += 256) {
        int g = i / BN, nl = i % BN;
        s2[g][nl] = w2s[(size_t)e * NG2 * N2 + (size_t)g * N2 + n0 + nl];
    }
    for (int m = tid; m < BM; m += 256)
        toks[m] = (m < mcount) ? plist[m0 + m] : 0;
    __syncthreads();

    f32x4 acc[2][4];
    #pragma unroll
    for (int i = 0; i < 2; i++)
        #pragma unroll
        for (int j = 0; j < 4; j++) acc[i][j] = (f32x4)(0.f);

    const int wv = tid >> 6, lane = tid & 63;
    const int lrow = lane & 15, quad = lane >> 4;
    const int mbase = wv * 32;

    for (int k0 = 0; k0 < I_DIM; k0 += BK) {
        // ---- stage A: act (bf16) -> LDS ----
        {
            const int m = tid >> 1, half = tid & 1;
            f32x4 v0, v1;
            if (m < mcount) {
                const f32x4* s4 = reinterpret_cast<const f32x4*>(
                    act + (size_t)(m0 + m) * I_DIM + k0 + half * 16);
                v0 = s4[0]; v1 = s4[1];
            } else { v0 = (f32x4)(0.f); v1 = (f32x4)(0.f); }
            *reinterpret_cast<f32x4*>(&As[m][half*16])     = v0;
            *reinterpret_cast<f32x4*>(&As[m][half*16 + 8]) = v1;
        }
        // ---- stage B: dequant W2 -> LDS (transposed) ----
        {
            const int nl = tid & 63, kpl = tid >> 6;
            const int kp = (k0 >> 3) + kpl;
            const int q = w2q[(size_t)e * KP2 * N2 + (size_t)kp * N2 + n0 + nl];
            const i32x4* gp = reinterpret_cast<const i32x4*>(g2 + e * I_DIM + k0 + kpl * 8);
            i32x4 ga = gp[0], gb = gp[1];
            int gsv[8] = {ga.x, ga.y, ga.z, ga.w, gb.x, gb.y, gb.z, gb.w};
            __align__(16) __bf16 tb[8];
            #pragma unroll
            for (int j = 0; j < 8; j++)
                tb[j] = (__bf16)((float)(((q >> (4*j)) & 15) - 8) * s2[gsv[j]][nl]);
            *reinterpret_cast<f32x4*>(&Bt[nl][kpl*8]) = *reinterpret_cast<f32x4*>(tb);
        }
        __syncthreads();
        {
            bf16x8 a0 = *reinterpret_cast<const bf16x8*>(&As[mbase + lrow][quad*8]);
            bf16x8 a1 = *reinterpret_cast<const bf16x8*>(&As[mbase + 16 + lrow][quad*8]);
            #pragma unroll
            for (int j = 0; j < 4; j++) {
                bf16x8 b = *reinterpret_cast<const bf16x8*>(&Bt[j*16 + lrow][quad*8]);
                acc[0][j] = __builtin_amdgcn_mfma_f32_16x16x32_bf16(a0, b, acc[0][j], 0, 0, 0);
                acc[1][j] = __builtin_amdgcn_mfma_f32_16x16x32_bf16(a1, b, acc[1][j], 0, 0, 0);
            }
        }
        __syncthreads();
    }

    #pragma unroll
    for (int i = 0; i < 2; i++)
        #pragma unroll
        for (int j = 0; j < 4; j++)
            #pragma unroll
            for (int r = 0; r < 4; r++) {
                int row = mbase + i*16 + quad*4 + r;
                if (row < mcount)
                    atomicAdd(&out[(size_t)toks[row] * H_DIM + n0 + j*16 + lrow],
                              acc[i][j][r]);
            }
}

// =====================================================================
extern "C" void kernel_launch(void* const* d_in, const int* in_sizes, int n_in,
                              void* d_out, int out_size, void* d_ws, size_t ws_size,
                              hipStream_t stream) {
    const float* x      = (const float*)d_in[0];
    const float* logits = (const float*)d_in[1];
    const int*   w13q   = (const int*)  d_in[2];
    const int*   w2q    = (const int*)  d_in[3];
    const float* w13s   = (const float*)d_in[4];
    const float* w2s    = (const float*)d_in[5];
    const int*   g13    = (const int*)  d_in[6];
    const int*   g2     = (const int*)  d_in[7];

    char* ws = (char*)d_ws;
    int*    counts = (int*)   (ws + WS_COUNTS);
    int*    offs   = (int*)   (ws + WS_OFFS);
    int*    curs   = (int*)   (ws + WS_CURS);
    int*    tok_e  = (int*)   (ws + WS_TOKE);
    float*  tok_w  = (float*) (ws + WS_TOKW);
    int*    plist  = (int*)   (ws + WS_PLIST);
    float*  pw     = (float*) (ws + WS_PW);
    __bf16* act    = (__bf16*)(ws + WS_ACT);
    float*  out    = (float*) d_out;

    hipMemsetAsync(d_out, 0, (size_t)T_TOK * H_DIM * sizeof(float), stream);
    hipMemsetAsync(d_ws, 0, 256, stream);

    k_route  <<<T_TOK/256, 256, 0, stream>>>(logits, counts, tok_e, tok_w);
    k_scan   <<<1, 64, 0, stream>>>(counts, offs, curs);
    k_scatter<<<T_TOK/256, 256, 0, stream>>>(tok_e, tok_w, curs, plist, pw);

    k_gemm1<<<dim3(NEXP*MT1, I_DIM/BN), 256, 0, stream>>>(
        x, w13q, w13s, g13, offs, plist, pw, act);
    k_gemm2<<<dim3(NEXP*MT2, H_DIM/BN), 256, 0, stream>>>(
        act, w2q, w2s, g2, offs, plist, out);
}

// Round 3
// 911.871 us; speedup vs baseline: 1.0934x; 1.0934x over previous
//
#include <hip/hip_runtime.h>

// ---------------- problem constants (fixed by setup_inputs) ----------------
#define T_TOK 2048
#define NEXP  8
#define H_DIM 1024
#define I_DIM 4096

#define KP13 (H_DIM/8)     // 128 packed rows, W13
#define N13  (2*I_DIM)     // 8192 cols, W13
#define KP2  (I_DIM/8)     // 512 packed rows, W2
#define N2   (H_DIM)       // 1024 cols, W2
#define NG13 8             // H/128 groups
#define NG2  32            // I/128 groups

// ---------------- tiles ----------------
#define BM 128
#define BN 64
#define BK 32
#define MT1 (T_TOK/BM)     // 16 worst-case m-tiles per expert
#define NT1 (H_DIM/BK)     // 32 k-iters, gemm1
#define KSPLIT2 2
#define KLEN2 (I_DIM/KSPLIT2)   // 2048
#define NT2 (KLEN2/BK)          // 64 k-iters, gemm2

typedef __bf16 bf16x8 __attribute__((ext_vector_type(8)));
typedef float  f32x4  __attribute__((ext_vector_type(4)));
typedef int    i32x4  __attribute__((ext_vector_type(4)));

// ---------------- workspace layout (bytes) ----------------
#define WS_COUNTS 0
#define WS_OFFS   64
#define WS_CURS   128
#define WS_TOKE   256
#define WS_TOKW   (WS_TOKE  + 2*T_TOK*4)
#define WS_PLIST  (WS_TOKW  + 2*T_TOK*4)
#define WS_PW     (WS_PLIST + 2*T_TOK*4)
#define PAIR_PAD  (2*T_TOK + 128)                 // 128 rows slack for tile overread
#define WS_XG     131072
#define WS_ACT    (WS_XG + PAIR_PAD*H_DIM*2)      // bf16 act[pairs][I_DIM]

// =====================================================================
// Routing
// =====================================================================
__global__ void k_route(const float* __restrict__ logits,
                        int* __restrict__ counts,
                        int* __restrict__ tok_e, float* __restrict__ tok_w) {
    int t = blockIdx.x * blockDim.x + threadIdx.x;
    if (t >= T_TOK) return;
    float l[NEXP];
    #pragma unroll
    for (int e = 0; e < NEXP; e++) l[e] = logits[t * NEXP + e];
    int i0 = 0; float b0 = l[0];
    #pragma unroll
    for (int e = 1; e < NEXP; e++) if (l[e] > b0) { b0 = l[e]; i0 = e; }
    int i1 = -1; float b1 = -1e30f;
    #pragma unroll
    for (int e = 0; e < NEXP; e++) if (e != i0 && l[e] > b1) { b1 = l[e]; i1 = e; }
    float w1 = 1.f / (1.f + __expf(b0 - b1));
    float w0 = 1.f - w1;
    tok_e[2*t] = i0; tok_e[2*t+1] = i1;
    tok_w[2*t] = w0; tok_w[2*t+1] = w1;
    atomicAdd(&counts[i0], 1);
    atomicAdd(&counts[i1], 1);
}

__global__ void k_scan(const int* __restrict__ counts,
                       int* __restrict__ offs, int* __restrict__ curs) {
    if (threadIdx.x == 0) {
        int s = 0;
        for (int e = 0; e < NEXP; e++) { offs[e] = s; curs[e] = s; s += counts[e]; }
        offs[NEXP] = s;
    }
}

__global__ void k_scatter(const int* __restrict__ tok_e, const float* __restrict__ tok_w,
                          int* __restrict__ curs,
                          int* __restrict__ plist, float* __restrict__ pw) {
    int t = blockIdx.x * blockDim.x + threadIdx.x;
    if (t >= T_TOK) return;
    #pragma unroll
    for (int s = 0; s < 2; s++) {
        int e = tok_e[2*t+s];
        int pos = atomicAdd(&curs[e], 1);
        plist[pos] = t;
        pw[pos] = tok_w[2*t+s];
    }
}

// gather x rows in pair order, fp32 -> bf16
__global__ void k_gather(const float* __restrict__ x, const int* __restrict__ plist,
                         __bf16* __restrict__ xg) {
    int p = blockIdx.x;
    int t = plist[p];
    int i = threadIdx.x;                       // 0..127, 8 elems each
    const f32x4* src = reinterpret_cast<const f32x4*>(x + (size_t)t * H_DIM);
    f32x4 v0 = src[i*2], v1 = src[i*2+1];
    __align__(16) __bf16 tb[8];
    #pragma unroll
    for (int j = 0; j < 4; j++) { tb[j] = (__bf16)v0[j]; tb[4+j] = (__bf16)v1[j]; }
    *reinterpret_cast<f32x4*>(xg + (size_t)p * H_DIM + i*8) = *reinterpret_cast<f32x4*>(tb);
}

// =====================================================================
// GEMM1: act[p, n] = w_p * silu(xg@Wg) * (xg@Wu)   (pipelined, reg-staged)
// =====================================================================
__global__ __launch_bounds__(256) void k_gemm1(
    const __bf16* __restrict__ xg,
    const int*    __restrict__ w13q,
    const float*  __restrict__ w13s,
    const int*    __restrict__ g13,
    const int*    __restrict__ offs,
    const float*  __restrict__ pw,
    __bf16*       __restrict__ act) {

    const int e  = blockIdx.x / MT1;
    const int mt = blockIdx.x % MT1;
    const int mstart = offs[e], mend = offs[e+1];
    const int m0 = mstart + mt * BM;
    if (m0 >= mend) return;
    const int mcount = min(mend - m0, BM);
    const int n0 = blockIdx.y * BN;

    __shared__ __align__(16) __bf16 As[2][BM*BK];
    __shared__ __align__(16) __bf16 Bg[2][BN*BK];
    __shared__ __align__(16) __bf16 Bu[2][BN*BK];
    __shared__ float sg[NG13][BN];
    __shared__ float su[NG13][BN];
    __shared__ float wts[BM];

    const int tid = threadIdx.x;
    const int wv = tid >> 6, lane = tid & 63;
    const int lrow = lane & 15, quad = lane >> 4;

    for (int i = tid; i < NG13 * BN; i += 256) {
        int g = i >> 6, nl = i & 63;
        size_t base = (size_t)e * NG13 * N13 + (size_t)g * N13 + n0 + nl;
        sg[g][nl] = w13s[base];
        su[g][nl] = w13s[base + I_DIM];
    }
    for (int m = tid; m < BM; m += 256)
        wts[m] = (m < mcount) ? pw[m0 + m] : 0.f;

    // ---- A staging: per-thread 2 slots (row, chunk), XOR-swizzled layout ----
    // slot h: row rA[h] = wv*32 + h*16 + (lane>>2), LDS slot c = lane&3,
    // holds global chunk cg = c ^ ((r>>1)&3).
    int rA[2], cgA[2], ldsA[2];
    #pragma unroll
    for (int h = 0; h < 2; h++) {
        rA[h]   = wv*32 + h*16 + (lane >> 2);
        cgA[h]  = (lane & 3) ^ ((rA[h] >> 1) & 3);
        ldsA[h] = rA[h]*BK + (lane & 3)*8;
    }
    auto loadA = [&](int kt, f32x4* va) {
        int k0 = kt * BK;
        #pragma unroll
        for (int h = 0; h < 2; h++)
            va[h] = *reinterpret_cast<const f32x4*>(
                xg + (size_t)(m0 + rA[h]) * H_DIM + k0 + cgA[h]*8);
    };
    auto storeA = [&](int buf, const f32x4* va) {
        #pragma unroll
        for (int h = 0; h < 2; h++)
            *reinterpret_cast<f32x4*>(&As[buf][ldsA[h]]) = va[h];
    };

    struct BReg { int qg, qu; i32x4 ga, gb; };
    auto loadB = [&](int kt, BReg& r) {
        int k0 = kt * BK;
        int kp = (k0 >> 3) + wv;
        size_t qbase = (size_t)e * KP13 * N13 + (size_t)kp * N13 + n0 + lane;
        r.qg = w13q[qbase];
        r.qu = w13q[qbase + I_DIM];
        const i32x4* gp = reinterpret_cast<const i32x4*>(g13 + e * H_DIM + k0 + wv*8);
        r.ga = gp[0]; r.gb = gp[1];
    };
    auto storeB = [&](int buf, const BReg& r) {
        int gsv[8] = {r.ga.x, r.ga.y, r.ga.z, r.ga.w, r.gb.x, r.gb.y, r.gb.z, r.gb.w};
        __align__(16) __bf16 tg[8], tu[8];
        #pragma unroll
        for (int j = 0; j < 8; j++) {
            float s0 = sg[gsv[j]][lane];
            float s1 = su[gsv[j]][lane];
            tg[j] = (__bf16)((float)(((r.qg >> (4*j)) & 15) - 8) * s0);
            tu[j] = (__bf16)((float)(((r.qu >> (4*j)) & 15) - 8) * s1);
        }
        int chunk = wv ^ ((lane >> 1) & 3);
        *reinterpret_cast<f32x4*>(&Bg[buf][lane*BK + chunk*8]) = *reinterpret_cast<f32x4*>(tg);
        *reinterpret_cast<f32x4*>(&Bu[buf][lane*BK + chunk*8]) = *reinterpret_cast<f32x4*>(tu);
    };

    f32x4 accg[2][4], accu[2][4];
    #pragma unroll
    for (int i = 0; i < 2; i++)
        #pragma unroll
        for (int j = 0; j < 4; j++) { accg[i][j] = (f32x4)(0.f); accu[i][j] = (f32x4)(0.f); }

    const int ar0 = wv*32 + lrow, ar1 = ar0 + 16;
    const int asw = (ar0 >> 1) & 3;           // swz(ar0) == swz(ar0+16)

    auto mfmaStage = [&](int buf) {
        bf16x8 a0 = *reinterpret_cast<const bf16x8*>(&As[buf][ar0*BK + ((quad ^ asw)*8)]);
        bf16x8 a1 = *reinterpret_cast<const bf16x8*>(&As[buf][ar1*BK + ((quad ^ asw)*8)]);
        #pragma unroll
        for (int j = 0; j < 4; j++) {
            int br = j*16 + lrow;
            int bc = (quad ^ ((br >> 1) & 3)) * 8;
            bf16x8 bg = *reinterpret_cast<const bf16x8*>(&Bg[buf][br*BK + bc]);
            bf16x8 bu = *reinterpret_cast<const bf16x8*>(&Bu[buf][br*BK + bc]);
            accg[0][j] = __builtin_amdgcn_mfma_f32_16x16x32_bf16(a0, bg, accg[0][j], 0, 0, 0);
            accg[1][j] = __builtin_amdgcn_mfma_f32_16x16x32_bf16(a1, bg, accg[1][j], 0, 0, 0);
            accu[0][j] = __builtin_amdgcn_mfma_f32_16x16x32_bf16(a0, bu, accu[0][j], 0, 0, 0);
            accu[1][j] = __builtin_amdgcn_mfma_f32_16x16x32_bf16(a1, bu, accu[1][j], 0, 0, 0);
        }
    };

    // ---- pipeline prologue: prefetch tiles 0,1 into regs; stage tile 0 ----
    f32x4 va0[2], va1[2];
    BReg  r0, r1;
    loadA(0, va0); loadB(0, r0);
    loadA(1, va1); loadB(1, r1);
    __syncthreads();               // sg/su/wts visible
    storeA(0, va0); storeB(0, r0);
    __syncthreads();               // tile 0 visible

    // ---- main loop: one barrier per K-tile ----
    for (int kt = 0; kt < NT1; kt += 2) {
        storeA(1, va1); storeB(1, r1);                     // stage tile kt+1
        if (kt+2 < NT1) { loadA(kt+2, va0); loadB(kt+2, r0); }
        mfmaStage(0);                                      // consume tile kt
        __syncthreads();

        if (kt+2 < NT1) { storeA(0, va0); storeB(0, r0); } // stage tile kt+2
        if (kt+3 < NT1) { loadA(kt+3, va1); loadB(kt+3, r1); }
        mfmaStage(1);                                      // consume tile kt+1
        __syncthreads();
    }

    // ---- epilogue: silu(g)*u * routing weight -> bf16 act ----
    #pragma unroll
    for (int i = 0; i < 2; i++)
        #pragma unroll
        for (int j = 0; j < 4; j++)
            #pragma unroll
            for (int r = 0; r < 4; r++) {
                int row = wv*32 + i*16 + quad*4 + r;
                if (row < mcount) {
                    float g = accg[i][j][r];
                    float u = accu[i][j][r];
                    float a = (g / (1.f + __expf(-g))) * u * wts[row];
                    act[(size_t)(m0 + row) * I_DIM + n0 + j*16 + lrow] = (__bf16)a;
                }
            }
}

// =====================================================================
// GEMM2: out[tok, h] += (act @ dequant(W2)), split-K, atomic combine
// =====================================================================
__global__ __launch_bounds__(256) void k_gemm2(
    const __bf16* __restrict__ act,
    const int*    __restrict__ w2q,
    const float*  __restrict__ w2s,
    const int*    __restrict__ g2,
    const int*    __restrict__ offs,
    const int*    __restrict__ plist,
    float*        __restrict__ out) {

    const int e  = blockIdx.x / MT1;
    const int mt = blockIdx.x % MT1;
    const int mstart = offs[e], mend = offs[e+1];
    const int m0 = mstart + mt * BM;
    if (m0 >= mend) return;
    const int mcount = min(mend - m0, BM);
    const int n0 = blockIdx.y * BN;
    const int kz = blockIdx.z * KLEN2;

    __shared__ __align__(16) __bf16 As[2][BM*BK];
    __shared__ __align__(16) __bf16 Bt[2][BN*BK];
    __shared__ float s2[NG2][BN];
    __shared__ int   toks[BM];

    const int tid = threadIdx.x;
    const int wv = tid >> 6, lane = tid & 63;
    const int lrow = lane & 15, quad = lane >> 4;

    for (int i = tid; i < NG2 * BN; i += 256) {
        int g = i >> 6, nl = i & 63;
        s2[g][nl] = w2s[(size_t)e * NG2 * N2 + (size_t)g * N2 + n0 + nl];
    }
    for (int m = tid; m < BM; m += 256)
        toks[m] = (m < mcount) ? plist[m0 + m] : 0;

    int rA[2], cgA[2], ldsA[2];
    #pragma unroll
    for (int h = 0; h < 2; h++) {
        rA[h]   = wv*32 + h*16 + (lane >> 2);
        cgA[h]  = (lane & 3) ^ ((rA[h] >> 1) & 3);
        ldsA[h] = rA[h]*BK + (lane & 3)*8;
    }
    auto loadA = [&](int kt, f32x4* va) {
        int k0 = kz + kt * BK;
        #pragma unroll
        for (int h = 0; h < 2; h++)
            va[h] = *reinterpret_cast<const f32x4*>(
                act + (size_t)(m0 + rA[h]) * I_DIM + k0 + cgA[h]*8);
    };
    auto storeA = [&](int buf, const f32x4* va) {
        #pragma unroll
        for (int h = 0; h < 2; h++)
            *reinterpret_cast<f32x4*>(&As[buf][ldsA[h]]) = va[h];
    };

    struct BReg { int q; i32x4 ga, gb; };
    auto loadB = [&](int kt, BReg& r) {
        int k0 = kz + kt * BK;
        int kp = (k0 >> 3) + wv;
        r.q = w2q[(size_t)e * KP2 * N2 + (size_t)kp * N2 + n0 + lane];
        const i32x4* gp = reinterpret_cast<const i32x4*>(g2 + e * I_DIM + k0 + wv*8);
        r.ga = gp[0]; r.gb = gp[1];
    };
    auto storeB = [&](int buf, const BReg& r) {
        int gsv[8] = {r.ga.x, r.ga.y, r.ga.z, r.ga.w, r.gb.x, r.gb.y, r.gb.z, r.gb.w};
        __align__(16) __bf16 tb[8];
        #pragma unroll
        for (int j = 0; j < 8; j++)
            tb[j] = (__bf16)((float)(((r.q >> (4*j)) & 15) - 8) * s2[gsv[j]][lane]);
        int chunk = wv ^ ((lane >> 1) & 3);
        *reinterpret_cast<f32x4*>(&Bt[buf][lane*BK + chunk*8]) = *reinterpret_cast<f32x4*>(tb);
    };

    f32x4 acc[2][4];
    #pragma unroll
    for (int i = 0; i < 2; i++)
        #pragma unroll
        for (int j = 0; j < 4; j++) acc[i][j] = (f32x4)(0.f);

    const int ar0 = wv*32 + lrow, ar1 = ar0 + 16;
    const int asw = (ar0 >> 1) & 3;

    auto mfmaStage = [&](int buf) {
        bf16x8 a0 = *reinterpret_cast<const bf16x8*>(&As[buf][ar0*BK + ((quad ^ asw)*8)]);
        bf16x8 a1 = *reinterpret_cast<const bf16x8*>(&As[buf][ar1*BK + ((quad ^ asw)*8)]);
        #pragma unroll
        for (int j = 0; j < 4; j++) {
            int br = j*16 + lrow;
            int bc = (quad ^ ((br >> 1) & 3)) * 8;
            bf16x8 b = *reinterpret_cast<const bf16x8*>(&Bt[buf][br*BK + bc]);
            acc[0][j] = __builtin_amdgcn_mfma_f32_16x16x32_bf16(a0, b, acc[0][j], 0, 0, 0);
            acc[1][j] = __builtin_amdgcn_mfma_f32_16x16x32_bf16(a1, b, acc[1][j], 0, 0, 0);
        }
    };

    f32x4 va0[2], va1[2];
    BReg  r0, r1;
    loadA(0, va0); loadB(0, r0);
    loadA(1, va1); loadB(1, r1);
    __syncthreads();               // s2/toks visible
    storeA(0, va0); storeB(0, r0);
    __syncthreads();               // tile 0 visible

    for (int kt = 0; kt < NT2; kt += 2) {
        storeA(1, va1); storeB(1, r1);
        if (kt+2 < NT2) { loadA(kt+2, va0); loadB(kt+2, r0); }
        mfmaStage(0);
        __syncthreads();

        if (kt+2 < NT2) { storeA(0, va0); storeB(0, r0); }
        if (kt+3 < NT2) { loadA(kt+3, va1); loadB(kt+3, r1); }
        mfmaStage(1);
        __syncthreads();
    }

    #pragma unroll
    for (int i = 0; i < 2; i++)
        #pragma unroll
        for (int j = 0; j < 4; j++)
            #pragma unroll
            for (int r = 0; r < 4; r++) {
                int row = wv*32 + i*16 + quad*4 + r;
                if (row < mcount)
                    atomicAdd(&out[(size_t)toks[row] * H_DIM + n0 + j*16 + lrow],
                              acc[i][j][r]);
            }
}

// =====================================================================
extern "C" void kernel_launch(void* const* d_in, const int* in_sizes, int n_in,
                              void* d_out, int out_size, void* d_ws, size_t ws_size,
                              hipStream_t stream) {
    const float* x      = (const float*)d_in[0];
    const float* logits = (const float*)d_in[1];
    const int*   w13q   = (const int*)  d_in[2];
    const int*   w2q    = (const int*)  d_in[3];
    const float* w13s   = (const float*)d_in[4];
    const float* w2s    = (const float*)d_in[5];
    const int*   g13    = (const int*)  d_in[6];
    const int*   g2     = (const int*)  d_in[7];

    char* ws = (char*)d_ws;
    int*    counts = (int*)   (ws + WS_COUNTS);
    int*    offs   = (int*)   (ws + WS_OFFS);
    int*    curs   = (int*)   (ws + WS_CURS);
    int*    tok_e  = (int*)   (ws + WS_TOKE);
    float*  tok_w  = (float*) (ws + WS_TOKW);
    int*    plist  = (int*)   (ws + WS_PLIST);
    float*  pw     = (float*) (ws + WS_PW);
    __bf16* xg     = (__bf16*)(ws + WS_XG);
    __bf16* act    = (__bf16*)(ws + WS_ACT);
    float*  out    = (float*) d_out;

    hipMemsetAsync(d_out, 0, (size_t)out_size * sizeof(float), stream);
    hipMemsetAsync(d_ws, 0, 256, stream);

    k_route  <<<T_TOK/256, 256, 0, stream>>>(logits, counts, tok_e, tok_w);
    k_scan   <<<1, 64, 0, stream>>>(counts, offs, curs);
    k_scatter<<<T_TOK/256, 256, 0, stream>>>(tok_e, tok_w, curs, plist, pw);
    k_gather <<<2*T_TOK, 128, 0, stream>>>(x, plist, xg);

    k_gemm1<<<dim3(NEXP*MT1, I_DIM/BN), 256, 0, stream>>>(
        xg, w13q, w13s, g13, offs, pw, act);
    k_gemm2<<<dim3(NEXP*MT1, N2/BN, KSPLIT2), 256, 0, stream>>>(
        act, w2q, w2s, g2, offs, plist, out);
}